// Round 1
// baseline (3345.449 us; speedup 1.0000x reference)
//
#include <hip/hip_runtime.h>
#include <math.h>

// Problem constants (setup_inputs): B=8, C=64, N=4096, O=64, K=20
#define Bn 8
#define Cc 64
#define Nn 4096
#define Oo 64
#define Kk 20
#define NTOT (Bn*Nn*Kk)   // 655360 elements per BN channel

// ---------------------------------------------------------------- utilities
__device__ __forceinline__ float wave_max64(float v) {
  v = fmaxf(v, __shfl_xor(v, 32));
  v = fmaxf(v, __shfl_xor(v, 16));
  v = fmaxf(v, __shfl_xor(v, 8));
  v = fmaxf(v, __shfl_xor(v, 4));
  v = fmaxf(v, __shfl_xor(v, 2));
  v = fmaxf(v, __shfl_xor(v, 1));
  return v;
}

// ---------------------------------------------------------------- k_sq
// sq[b,n] = sum_c x[b,c,n]^2 ; lanes map to consecutive n -> coalesced.
__global__ __launch_bounds__(256) void k_sq(const float* __restrict__ x,
                                            float* __restrict__ sqv) {
  int g = blockIdx.x * 256 + threadIdx.x;          // g in [0, B*N)
  int b = g >> 12;
  int n = g & (Nn - 1);
  const float* xp = x + (size_t)b * Cc * Nn + n;
  float s = 0.f;
#pragma unroll
  for (int c = 0; c < Cc; c++) { float v = xp[(size_t)c * Nn]; s = fmaf(v, v, s); }
  sqv[g] = s;
}

// ---------------------------------------------------------------- k_y1z
// y1[b,n,o] = sum_c xt[b,n,c]*W[o,c]        (W1 part)
// z [b,n,o] = sum_c xt[b,n,c]*(W[o,64+c]-W[o,c])  computed as a2-a1
// Block: one (b, 64-n tile); thread lane = o  -> coalesced stores.
__global__ __launch_bounds__(256) void k_y1z(const float* __restrict__ x,
                                             const float* __restrict__ Wm,
                                             float* __restrict__ y1,
                                             float* __restrict__ z) {
  __shared__ float xs[64][64];    // [c][n_local]
  __shared__ float Wl[64][129];   // [o][c], +1 pad -> stride 129 (2-way banks, free)
  int tid = threadIdx.x;
  int b = blockIdx.x >> 6;
  int n0 = (blockIdx.x & 63) << 6;
  for (int i = tid; i < 64 * 128; i += 256) Wl[i >> 7][i & 127] = Wm[i];
  for (int i = 0; i < 16; i++) {
    int c = i * 4 + (tid >> 6);
    int n = tid & 63;
    xs[c][n] = x[((size_t)b * Cc + c) * Nn + n0 + n];
  }
  __syncthreads();
  int o = tid & 63, ng = tid >> 6;
  for (int p = 0; p < 16; p++) {
    int n = ng + p * 4;
    float a1 = 0.f, a2 = 0.f;
#pragma unroll 8
    for (int c = 0; c < 64; c++) {
      float xv = xs[c][n];             // wave-uniform addr -> LDS broadcast
      a1 = fmaf(xv, Wl[o][c], a1);
      a2 = fmaf(xv, Wl[o][64 + c], a2);
    }
    size_t off = ((size_t)b * Nn + n0 + n) * 64 + o;
    y1[off] = a1;
    z[off] = a2 - a1;
  }
}

// ---------------------------------------------------------------- top-k insert
// Rare path: scan set bits of the ballot mask, insert candidates smaller than
// the row's current 20th-smallest (replace-max, unsorted list). Whole wave
// participates; all control is wave-uniform. __noinline__ keeps the hot loop
// body small (I-cache).
__device__ __noinline__ void topk_insert_scan(unsigned long long mask, float key,
                                              int ibase, int jm, int tid, int lane,
                                              float (*kqd)[Kk],
                                              unsigned short (*kqi)[Kk],
                                              float* thr) {
  while (mask) {
    int src = __ffsll(mask) - 1;
    mask &= mask - 1;
    float cv = __shfl(key, src);                       // candidate key (uniform)
    int row_s = (((tid & 192) + src) >> 4) * 8 + ibase; // owning row (uniform)
    int m_s = ((src & 15) << 3) + jm;                   // absolute m index
    if (cv < thr[row_s]) {                              // re-check: thr shrinks
      float v = (lane < Kk) ? kqd[row_s][lane] : -INFINITY;
      float mx = wave_max64(v);
      unsigned long long mm = __ballot(v == mx);
      int slot = __ffsll(mm) - 1;
      if (lane == slot) {
        kqd[row_s][slot] = cv;
        kqi[row_s][slot] = (unsigned short)m_s;
      }
      float v2 = (lane == slot) ? cv : v;
      float mx2 = wave_max64(v2);
      if (lane == 0) thr[row_s] = mx2;
    }
  }
}

// ---------------------------------------------------------------- k_knn
// Fused Gram + row-wise top-20. Block tile 128 rows x 128 cols, thread tile
// 8x8 fp32 (register-resident keys -> no d2 tile in LDS). Wave w exclusively
// owns rows [32w, 32w+32) so top-k state needs no cross-wave sync.
// Selection key: sq[m] - 2*dot (row-constant sq[n] dropped; order-preserving).
// LDS: 32K(Xn)+32K(Xm)+10K(kqd)+5K(kqi)+1K = 80KB (gfx950 allows 160KB/WG).
__global__ __launch_bounds__(256, 1) void k_knn(const float* __restrict__ x,
                                                const float* __restrict__ sqv,
                                                int* __restrict__ idxout) {
  __shared__ float Xn[64][128];          // [c][r], pre-scaled by -2
  __shared__ float Xm[64][128];          // [c][m]
  __shared__ float kqd[128][Kk];
  __shared__ unsigned short kqi[128][Kk];
  __shared__ float thr[128];
  __shared__ float sqs[128];

  const int tid = threadIdx.x;
  const int lane = tid & 63;
  const int w = tid >> 6;
  const int b = blockIdx.x >> 5;          // 32 row-tiles per batch
  const int n0 = (blockIdx.x & 31) << 7;
  const int ty = tid >> 4;                // 0..15 -> 8 rows each
  const int tx = tid & 15;                // 0..15 -> 8 cols each

  for (int i = tid; i < 128 * Kk; i += 256) kqd[i / Kk][i % Kk] = INFINITY;
  if (tid < 128) thr[tid] = INFINITY;

  const float* xb = x + (size_t)b * Cc * Nn;
  for (int i = 0; i < 32; i++) {
    int t = i * 256 + tid;
    int c = t >> 7, r = t & 127;
    Xn[c][r] = -2.0f * xb[(size_t)c * Nn + n0 + r];
  }
  __syncthreads();

  float acc[8][8];

  for (int m0 = 0; m0 < Nn; m0 += 128) {
    for (int i = 0; i < 32; i++) {
      int t = i * 256 + tid;
      int c = t >> 7, m = t & 127;
      Xm[c][m] = xb[(size_t)c * Nn + m0 + m];
    }
    if (tid < 128) sqs[tid] = sqv[b * Nn + m0 + tid];
    __syncthreads();

#pragma unroll
    for (int i = 0; i < 8; i++)
#pragma unroll
      for (int j = 0; j < 8; j++) acc[i][j] = 0.0f;

#pragma unroll 4
    for (int c = 0; c < 64; c++) {
      float a[8], bb[8];
      *(float4*)&a[0]  = *(const float4*)&Xn[c][ty * 8];
      *(float4*)&a[4]  = *(const float4*)&Xn[c][ty * 8 + 4];
      *(float4*)&bb[0] = *(const float4*)&Xm[c][tx * 8];
      *(float4*)&bb[4] = *(const float4*)&Xm[c][tx * 8 + 4];
#pragma unroll
      for (int i = 0; i < 8; i++)
#pragma unroll
        for (int j = 0; j < 8; j++) acc[i][j] = fmaf(a[i], bb[j], acc[i][j]);
    }

    // top-k update: 64 ballots/tile, inserts are rare (~126 total per row)
#pragma unroll
    for (int i = 0; i < 8; i++) {
      int row = ty * 8 + i;
#pragma unroll
      for (int j = 0; j < 8; j++) {
        float key = sqs[tx * 8 + j] + acc[i][j];
        unsigned long long mask = __ballot(key < thr[row]);
        if (mask) topk_insert_scan(mask, key, i, m0 + j, tid, lane, kqd, kqi, thr);
      }
    }
    __syncthreads();
  }

  for (int rr = 0; rr < 32; rr++) {
    int r = w * 32 + rr;
    if (lane < Kk)
      idxout[((size_t)b * Nn + n0 + r) * Kk + lane] = (int)kqi[r][lane];
  }
}

// ---------------------------------------------------------------- k_stats
// Accumulate sum / sumsq of h[b,n,k,o] = y1[b,idx,o] + z[b,n,o] per channel o.
// Lane = o -> every gather is a coalesced 256B row of y1 (L2-resident, 1MB/batch).
__global__ __launch_bounds__(256) void k_stats(const float* __restrict__ y1,
                                               const float* __restrict__ z,
                                               const int* __restrict__ idxp,
                                               float* __restrict__ stats) {
  __shared__ float rs[4][64];
  __shared__ float rq[4][64];
  int tid = threadIdx.x;
  int o = tid & 63, g = tid >> 6;
  int b = blockIdx.x >> 5;
  int n0 = (blockIdx.x & 31) << 7;
  const float* y1b = y1 + (size_t)b * Nn * 64;
  float s = 0.f, ss = 0.f;
  for (int t = 0; t < 32; t++) {
    int n = n0 + g + t * 4;
    size_t base = (size_t)b * Nn + n;
    float zv = z[base * 64 + o];
    const int* ip = idxp + base * Kk;
#pragma unroll
    for (int k = 0; k < Kk; k++) {
      int j = ip[k];                                 // wave-uniform -> broadcast
      float hv = y1b[(size_t)j * 64 + o] + zv;
      s += hv;
      ss = fmaf(hv, hv, ss);
    }
  }
  rs[g][o] = s;
  rq[g][o] = ss;
  __syncthreads();
  if (tid < 64) {
    float a = rs[0][tid] + rs[1][tid] + rs[2][tid] + rs[3][tid];
    float q = rq[0][tid] + rq[1][tid] + rq[2][tid] + rq[3][tid];
    atomicAdd(&stats[tid], a);
    atomicAdd(&stats[64 + tid], q);
  }
}

// ---------------------------------------------------------------- k_out
// out[b,o,n] = max_k leakyrelu( h*scale_o + bias_o ), transposed via LDS tile.
__global__ __launch_bounds__(256) void k_out(const float* __restrict__ y1,
                                             const float* __restrict__ z,
                                             const int* __restrict__ idxp,
                                             const float* __restrict__ stats,
                                             const float* __restrict__ gamma,
                                             const float* __restrict__ beta,
                                             float* __restrict__ out) {
  __shared__ float T[64][65];                         // +1 pad -> conflict-free
  int tid = threadIdx.x;
  int lane = tid & 63;
  int w = tid >> 6;
  int b = blockIdx.x >> 6;
  int n0 = (blockIdx.x & 63) << 6;
  int o = lane;
  const float inv = 1.0f / (float)NTOT;
  float mean = stats[o] * inv;
  float var = fmaf(-mean, mean, stats[64 + o] * inv);
  float sc = gamma[o] * rsqrtf(var + 1e-5f);
  float bi = fmaf(-mean, sc, beta[o]);
  const float* y1b = y1 + (size_t)b * Nn * 64;
  for (int t = 0; t < 16; t++) {
    int nl = w + t * 4;
    size_t base = (size_t)b * Nn + n0 + nl;
    float zv = z[base * 64 + o];
    const int* ip = idxp + base * Kk;
    float mv = -INFINITY;
#pragma unroll
    for (int k = 0; k < Kk; k++) {
      int j = ip[k];
      float hv = y1b[(size_t)j * 64 + o] + zv;
      float hn = fmaf(hv, sc, bi);
      float a = (hn >= 0.f) ? hn : 0.2f * hn;
      mv = fmaxf(mv, a);
    }
    T[o][nl] = mv;
  }
  __syncthreads();
  for (int t = 0; t < 16; t++) {
    int oo = w * 16 + t;
    out[((size_t)b * Oo + oo) * Nn + n0 + lane] = T[oo][lane];
  }
}

// ---------------------------------------------------------------- launch
extern "C" void kernel_launch(void* const* d_in, const int* in_sizes, int n_in,
                              void* d_out, int out_size, void* d_ws, size_t ws_size,
                              hipStream_t stream) {
  const float* x = (const float*)d_in[0];
  const float* W = (const float*)d_in[1];
  const float* gamma = (const float*)d_in[2];
  const float* beta = (const float*)d_in[3];
  // d_in[4] is k (=20), baked in as Kk.

  // workspace layout (bytes):
  //   y1   : [0,        8388608)   B*N*O fp32
  //   z    : [8388608, 16777216)   B*N*O fp32
  //   sq   : [16777216,16908288)   B*N   fp32
  //   stats: [16908288,16908800)   128   fp32 (sum | sumsq)
  //   idx  : [16908800,19530240)   B*N*K int32
  char* ws = (char*)d_ws;
  float* y1 = (float*)ws;
  float* z = (float*)(ws + 8388608);
  float* sq = (float*)(ws + 16777216);
  float* stats = (float*)(ws + 16908288);
  int* idx = (int*)(ws + 16908800);
  float* out = (float*)d_out;

  hipMemsetAsync(stats, 0, 128 * sizeof(float), stream);   // atomics need zeros
  k_sq<<<(Bn * Nn) / 256, 256, 0, stream>>>(x, sq);
  k_y1z<<<Bn * (Nn / 64), 256, 0, stream>>>(x, W, y1, z);
  k_knn<<<Bn * (Nn / 128), 256, 0, stream>>>(x, sq, idx);
  k_stats<<<Bn * (Nn / 128), 256, 0, stream>>>(y1, z, idx, stats);
  k_out<<<Bn * (Nn / 64), 256, 0, stream>>>(y1, z, idx, stats, gamma, beta, out);
}

// Round 2
// 1055.278 us; speedup vs baseline: 3.1702x; 3.1702x over previous
//
#include <hip/hip_runtime.h>
#include <math.h>

// Problem constants (setup_inputs): B=8, C=64, N=4096, O=64, K=20
#define Bn 8
#define Cc 64
#define Nn 4096
#define Oo 64
#define Kk 20
#define NTOT (Bn*Nn*Kk)   // 655360 elements per BN channel

// ---------------------------------------------------------------- k_sq
__global__ __launch_bounds__(256) void k_sq(const float* __restrict__ x,
                                            float* __restrict__ sqv) {
  int g = blockIdx.x * 256 + threadIdx.x;          // g in [0, B*N)
  int b = g >> 12;
  int n = g & (Nn - 1);
  const float* xp = x + (size_t)b * Cc * Nn + n;
  float s = 0.f;
#pragma unroll
  for (int c = 0; c < Cc; c++) { float v = xp[(size_t)c * Nn]; s = fmaf(v, v, s); }
  sqv[g] = s;
}

// ---------------------------------------------------------------- k_y1z
__global__ __launch_bounds__(256) void k_y1z(const float* __restrict__ x,
                                             const float* __restrict__ Wm,
                                             float* __restrict__ y1,
                                             float* __restrict__ z) {
  __shared__ float xs[64][64];
  __shared__ float Wl[64][129];
  int tid = threadIdx.x;
  int b = blockIdx.x >> 6;
  int n0 = (blockIdx.x & 63) << 6;
  for (int i = tid; i < 64 * 128; i += 256) Wl[i >> 7][i & 127] = Wm[i];
  for (int i = 0; i < 16; i++) {
    int c = i * 4 + (tid >> 6);
    int n = tid & 63;
    xs[c][n] = x[((size_t)b * Cc + c) * Nn + n0 + n];
  }
  __syncthreads();
  int o = tid & 63, ng = tid >> 6;
  for (int p = 0; p < 16; p++) {
    int n = ng + p * 4;
    float a1 = 0.f, a2 = 0.f;
#pragma unroll 8
    for (int c = 0; c < 64; c++) {
      float xv = xs[c][n];
      a1 = fmaf(xv, Wl[o][c], a1);
      a2 = fmaf(xv, Wl[o][64 + c], a2);
    }
    size_t off = ((size_t)b * Nn + n0 + n) * 64 + o;
    y1[off] = a1;
    z[off] = a2 - a1;
  }
}

// ---------------------------------------------------------------- k_knn (v2)
// 64 rows/block, 128-col tiles, 256 threads (4 waves), thread tile 4 rows x
// 8 cols (cols tx*4..+3 and 64+tx*4..+3 -> 16B-stride LDS reads, 2-way = free).
// Wave w owns rows [16w,16w+16): per tile, reduce to per-row min (in-thread +
// 4-step shfl butterfly over tx), then 16 handler lanes insert all 16 rows'
// minima in PARALLEL into LDS top-20 lists. Min-first => ascending insertion
// => #iterations == #accepted inserts (+1); tile 0 converges in ~21 iters.
// Selection key: sq[m] - 2*dot (row-constant sq[n] dropped; order-preserving).
// LDS ~56.6KB -> 2 blocks/CU; grid 512 = 2/CU resident.
__global__ __launch_bounds__(256) void k_knn(const float* __restrict__ x,
                                             const float* __restrict__ sqv,
                                             int* __restrict__ idxout) {
  __shared__ float Xn[Cc][64];           // row block, pre-scaled by -2
  __shared__ float Xm[Cc][128];          // col tile
  __shared__ float kqd[64][Kk];
  __shared__ unsigned short kqi[64][Kk];
  __shared__ float thrS[64];
  __shared__ float sqs[128];

  const int tid = threadIdx.x;
  const int lane = tid & 63;
  const int w = tid >> 6;
  const int b = blockIdx.x >> 6;          // 64 row-blocks per batch
  const int n0 = (blockIdx.x & 63) << 6;
  const int tx = tid & 15;                // col group
  const int ty = tid >> 4;                // row group [0,16), 4 rows each

  for (int t = tid; t < 64 * Kk; t += 256) ((float*)kqd)[t] = INFINITY;
  if (tid < 64) thrS[tid] = INFINITY;

  const float* xb = x + (size_t)b * Cc * Nn;

  // stage Xn once (scaled by -2): 1024 float4, lane-contiguous (2-way free)
#pragma unroll
  for (int i = 0; i < 4; i++) {
    int f = i * 256 + tid;                // float4 index in [0,1024)
    int c = f >> 4;
    int m = (f & 15) << 2;
    float4 v = *(const float4*)(xb + (size_t)c * Nn + n0 + m);
    v.x *= -2.f; v.y *= -2.f; v.z *= -2.f; v.w *= -2.f;
    *(float4*)&Xn[c][m] = v;
  }
  __syncthreads();

  float acc[4][8];
  float mv[4]; int mj[4];

  for (int m0 = 0; m0 < Nn; m0 += 128) {
    // stage Xm: 2048 float4, lane-contiguous
#pragma unroll
    for (int i = 0; i < 8; i++) {
      int f = i * 256 + tid;
      int c = f >> 5;
      int m = (f & 31) << 2;
      *(float4*)&Xm[c][m] = *(const float4*)(xb + (size_t)c * Nn + m0 + m);
    }
    if (tid < 32) ((float4*)sqs)[tid] = ((const float4*)(sqv + b * Nn + m0))[tid];
    __syncthreads();

#pragma unroll
    for (int ii = 0; ii < 4; ii++)
#pragma unroll
      for (int jj = 0; jj < 8; jj++) acc[ii][jj] = 0.0f;

#pragma unroll 8
    for (int c = 0; c < Cc; c++) {
      float4 av = *(const float4*)&Xn[c][ty << 2];
      float4 b0 = *(const float4*)&Xm[c][tx << 2];
      float4 b1 = *(const float4*)&Xm[c][64 + (tx << 2)];
      float aa[4] = {av.x, av.y, av.z, av.w};
      float bb[8] = {b0.x, b0.y, b0.z, b0.w, b1.x, b1.y, b1.z, b1.w};
#pragma unroll
      for (int ii = 0; ii < 4; ii++)
#pragma unroll
        for (int jj = 0; jj < 8; jj++)
          acc[ii][jj] = fmaf(aa[ii], bb[jj], acc[ii][jj]);
    }

    // keys (acc += sq[m]) and per-row in-thread min
    {
      float4 s0 = *(const float4*)&sqs[tx << 2];
      float4 s1 = *(const float4*)&sqs[64 + (tx << 2)];
      float sv[8] = {s0.x, s0.y, s0.z, s0.w, s1.x, s1.y, s1.z, s1.w};
#pragma unroll
      for (int ii = 0; ii < 4; ii++) {
        float best = INFINITY; int bj = 0;
#pragma unroll
        for (int jj = 0; jj < 8; jj++) {
          float key = acc[ii][jj] + sv[jj];
          acc[ii][jj] = key;
          if (key < best) { best = key; bj = jj; }
        }
        mv[ii] = best;
        mj[ii] = m0 + (bj < 4 ? (tx << 2) + bj : 64 + (tx << 2) + (bj - 4));
      }
    }
    // cross-tx butterfly (lanes sharing ty agree on row min)
#pragma unroll
    for (int s = 1; s < 16; s <<= 1) {
#pragma unroll
      for (int ii = 0; ii < 4; ii++) {
        float ov = __shfl_xor(mv[ii], s);
        int oj = __shfl_xor(mj[ii], s);
        if (ov < mv[ii]) { mv[ii] = ov; mj[ii] = oj; }
      }
    }

    // handler loop: 16 rows inserted in parallel per iteration
    while (true) {
      int src = (lane >> 2) << 4;          // tx=0 lane of source ty group
      float tv0 = __shfl(mv[0], src), tv1 = __shfl(mv[1], src);
      float tv2 = __shfl(mv[2], src), tv3 = __shfl(mv[3], src);
      int tj0 = __shfl(mj[0], src), tj1 = __shfl(mj[1], src);
      int tj2 = __shfl(mj[2], src), tj3 = __shfl(mj[3], src);
      int sel = lane & 3;
      float hv = (sel < 2) ? (sel == 0 ? tv0 : tv1) : (sel == 2 ? tv2 : tv3);
      int hm = (sel < 2) ? (sel == 0 ? tj0 : tj1) : (sel == 2 ? tj2 : tj3);
      int row = (w << 4) + (lane & 15);
      bool want = (lane < 16) && (hv < thrS[row]);
      unsigned long long mask = __ballot(want);
      if (!mask) break;
      if (want) {
        float mx = -INFINITY, mx2 = -INFINITY; int slot = 0;
#pragma unroll
        for (int kk = 0; kk < Kk; kk++) {
          float v = kqd[row][kk];
          if (v > mx) { mx2 = mx; mx = v; slot = kk; }
          else if (v > mx2) mx2 = v;
        }
        kqd[row][slot] = hv;
        kqi[row][slot] = (unsigned short)hm;
        thrS[row] = fmaxf(mx2, hv);
      }
      // removal + re-reduce for inserted rows
#pragma unroll
      for (int ii = 0; ii < 4; ii++) {
        if (!((mask >> ii) & 0x1111ULL)) continue;   // rows with this ii
        int hl = ((lane >> 4) << 2) | ii;            // handler for MY row
        bool ins = (mask >> hl) & 1;
        int rm = __shfl(hm, hl);
        if (ins) {
          int lc = rm - m0;
          if (lc < 64) { if ((lc >> 2) == tx) acc[ii][lc & 3] = INFINITY; }
          else { if (((lc - 64) >> 2) == tx) acc[ii][4 + (lc & 3)] = INFINITY; }
          float best = INFINITY; int bj = 0;
#pragma unroll
          for (int jj = 0; jj < 8; jj++)
            if (acc[ii][jj] < best) { best = acc[ii][jj]; bj = jj; }
          mv[ii] = best;
          mj[ii] = m0 + (bj < 4 ? (tx << 2) + bj : 64 + (tx << 2) + (bj - 4));
        }
#pragma unroll
        for (int s = 1; s < 16; s <<= 1) {
          float ov = __shfl_xor(mv[ii], s);
          int oj = __shfl_xor(mj[ii], s);
          if (ov < mv[ii]) { mv[ii] = ov; mj[ii] = oj; }
        }
      }
    }
    __syncthreads();
  }

  // write indices (order within the 20 doesn't matter: output is max over k)
  for (int t = tid; t < 64 * Kk; t += 256) {
    int r = t / Kk, kk = t % Kk;
    idxout[((size_t)b * Nn + n0 + r) * Kk + kk] = (int)kqi[r][kk];
  }
}

// ---------------------------------------------------------------- k_stats
__global__ __launch_bounds__(256) void k_stats(const float* __restrict__ y1,
                                               const float* __restrict__ z,
                                               const int* __restrict__ idxp,
                                               float* __restrict__ stats) {
  __shared__ float rs[4][64];
  __shared__ float rq[4][64];
  int tid = threadIdx.x;
  int o = tid & 63, g = tid >> 6;
  int b = blockIdx.x >> 5;
  int n0 = (blockIdx.x & 31) << 7;
  const float* y1b = y1 + (size_t)b * Nn * 64;
  float s = 0.f, ss = 0.f;
  for (int t = 0; t < 32; t++) {
    int n = n0 + g + t * 4;
    size_t base = (size_t)b * Nn + n;
    float zv = z[base * 64 + o];
    const int* ip = idxp + base * Kk;
#pragma unroll
    for (int k = 0; k < Kk; k++) {
      int j = ip[k];
      float hv = y1b[(size_t)j * 64 + o] + zv;
      s += hv;
      ss = fmaf(hv, hv, ss);
    }
  }
  rs[g][o] = s;
  rq[g][o] = ss;
  __syncthreads();
  if (tid < 64) {
    float a = rs[0][tid] + rs[1][tid] + rs[2][tid] + rs[3][tid];
    float q = rq[0][tid] + rq[1][tid] + rq[2][tid] + rq[3][tid];
    atomicAdd(&stats[tid], a);
    atomicAdd(&stats[64 + tid], q);
  }
}

// ---------------------------------------------------------------- k_out
__global__ __launch_bounds__(256) void k_out(const float* __restrict__ y1,
                                             const float* __restrict__ z,
                                             const int* __restrict__ idxp,
                                             const float* __restrict__ stats,
                                             const float* __restrict__ gamma,
                                             const float* __restrict__ beta,
                                             float* __restrict__ out) {
  __shared__ float T[64][65];
  int tid = threadIdx.x;
  int lane = tid & 63;
  int w = tid >> 6;
  int b = blockIdx.x >> 6;
  int n0 = (blockIdx.x & 63) << 6;
  int o = lane;
  const float inv = 1.0f / (float)NTOT;
  float mean = stats[o] * inv;
  float var = fmaf(-mean, mean, stats[64 + o] * inv);
  float sc = gamma[o] * rsqrtf(var + 1e-5f);
  float bi = fmaf(-mean, sc, beta[o]);
  const float* y1b = y1 + (size_t)b * Nn * 64;
  for (int t = 0; t < 16; t++) {
    int nl = w + t * 4;
    size_t base = (size_t)b * Nn + n0 + nl;
    float zv = z[base * 64 + o];
    const int* ip = idxp + base * Kk;
    float mv = -INFINITY;
#pragma unroll
    for (int k = 0; k < Kk; k++) {
      int j = ip[k];
      float hv = y1b[(size_t)j * 64 + o] + zv;
      float hn = fmaf(hv, sc, bi);
      float a = (hn >= 0.f) ? hn : 0.2f * hn;
      mv = fmaxf(mv, a);
    }
    T[o][nl] = mv;
  }
  __syncthreads();
  for (int t = 0; t < 16; t++) {
    int oo = w * 16 + t;
    out[((size_t)b * Oo + oo) * Nn + n0 + lane] = T[oo][lane];
  }
}

// ---------------------------------------------------------------- launch
extern "C" void kernel_launch(void* const* d_in, const int* in_sizes, int n_in,
                              void* d_out, int out_size, void* d_ws, size_t ws_size,
                              hipStream_t stream) {
  const float* x = (const float*)d_in[0];
  const float* W = (const float*)d_in[1];
  const float* gamma = (const float*)d_in[2];
  const float* beta = (const float*)d_in[3];
  // d_in[4] is k (=20), baked in as Kk.

  char* ws = (char*)d_ws;
  float* y1 = (float*)ws;
  float* z = (float*)(ws + 8388608);
  float* sq = (float*)(ws + 16777216);
  float* stats = (float*)(ws + 16908288);
  int* idx = (int*)(ws + 16908800);
  float* out = (float*)d_out;

  hipMemsetAsync(stats, 0, 128 * sizeof(float), stream);
  k_sq<<<(Bn * Nn) / 256, 256, 0, stream>>>(x, sq);
  k_y1z<<<Bn * (Nn / 64), 256, 0, stream>>>(x, W, y1, z);
  k_knn<<<Bn * (Nn / 64), 256, 0, stream>>>(x, sq, idx);
  k_stats<<<Bn * (Nn / 128), 256, 0, stream>>>(y1, z, idx, stats);
  k_out<<<Bn * (Nn / 64), 256, 0, stream>>>(y1, z, idx, stats, gamma, beta, out);
}

// Round 3
// 814.755 us; speedup vs baseline: 4.1061x; 1.2952x over previous
//
#include <hip/hip_runtime.h>
#include <math.h>

// Problem constants (setup_inputs): B=8, C=64, N=4096, O=64, K=20
#define Bn 8
#define Cc 64
#define Nn 4096
#define Oo 64
#define Kk 20
#define QCAP 32              // per-row candidate queue capacity per tile
#define NTOT (Bn*Nn*Kk)      // 655360 elements per BN channel

// ---------------------------------------------------------------- k_sq
__global__ __launch_bounds__(256) void k_sq(const float* __restrict__ x,
                                            float* __restrict__ sqv) {
  int g = blockIdx.x * 256 + threadIdx.x;          // g in [0, B*N)
  int b = g >> 12;
  int n = g & (Nn - 1);
  const float* xp = x + (size_t)b * Cc * Nn + n;
  float s = 0.f;
#pragma unroll
  for (int c = 0; c < Cc; c++) { float v = xp[(size_t)c * Nn]; s = fmaf(v, v, s); }
  sqv[g] = s;
}

// ---------------------------------------------------------------- k_y1z
__global__ __launch_bounds__(256) void k_y1z(const float* __restrict__ x,
                                             const float* __restrict__ Wm,
                                             float* __restrict__ y1,
                                             float* __restrict__ z) {
  __shared__ float xs[64][64];
  __shared__ float Wl[64][129];
  int tid = threadIdx.x;
  int b = blockIdx.x >> 6;
  int n0 = (blockIdx.x & 63) << 6;
  for (int i = tid; i < 64 * 128; i += 256) Wl[i >> 7][i & 127] = Wm[i];
  for (int i = 0; i < 16; i++) {
    int c = i * 4 + (tid >> 6);
    int n = tid & 63;
    xs[c][n] = x[((size_t)b * Cc + c) * Nn + n0 + n];
  }
  __syncthreads();
  int o = tid & 63, ng = tid >> 6;
  for (int p = 0; p < 16; p++) {
    int n = ng + p * 4;
    float a1 = 0.f, a2 = 0.f;
#pragma unroll 8
    for (int c = 0; c < 64; c++) {
      float xv = xs[c][n];
      a1 = fmaf(xv, Wl[o][c], a1);
      a2 = fmaf(xv, Wl[o][64 + c], a2);
    }
    size_t off = ((size_t)b * Nn + n0 + n) * 64 + o;
    y1[off] = a1;
    z[off] = a2 - a1;
  }
}

// ---------------------------------------------------------------- k_knn (v3)
// 64 rows/block, 128-col tiles, 256 threads, 4x8 register tile (same Gram as
// round 2, which is LDS-read-bound at ~245us floor). Top-k machinery replaced:
//  - pushers: test 32 keys vs monotone-decreasing per-row threshold (LDS),
//    append rare hits (~4/row/tile) to per-row LDS queues via ds atomicAdd.
//  - handlers: 64 lanes (wave 0, row = tid) drain queues in parallel; each
//    row's top-20 keys+indices live in the handler's REGISTERS (no LDS scans,
//    no bank conflicts, no shuffles). Replace-max insert = unrolled cndmask.
//  - overflow (tile 0: thr=INF -> 128 cands/row) handled by pend-bitmask
//    retry loop; steady state is a single pass.
// Threshold staleness is safe: thr only decreases, handler re-checks on pop.
// XCD swizzle: b = blockIdx&7 -> each XCD's L2 caches one batch's x (1MB).
__global__ __launch_bounds__(256) void k_knn(const float* __restrict__ x,
                                             const float* __restrict__ sqv,
                                             int* __restrict__ idxout) {
  __shared__ float Xn[Cc][64];           // row block, pre-scaled by -2
  __shared__ float Xm[Cc][128];          // col tile
  __shared__ float thrS[64];
  __shared__ float sqs[128];
  __shared__ float qk[64][QCAP];
  __shared__ unsigned short qm[64][QCAP];
  __shared__ int qcnt[64];
  __shared__ int more;

  const int tid = threadIdx.x;
  const int b = blockIdx.x & 7;           // XCD swizzle: batch per XCD
  const int n0 = (blockIdx.x >> 3) << 6;
  const int tx = tid & 15;                // col group (8 cols: 4 + 4 split)
  const int ty = tid >> 4;                // row group [0,16), 4 rows each

  // handler state (meaningful for tid<64 only; row = tid)
  float hk[Kk];
  int hix[Kk];
  float hthr = INFINITY;
#pragma unroll
  for (int kk = 0; kk < Kk; kk++) { hk[kk] = INFINITY; hix[kk] = 0; }

  if (tid < 64) { thrS[tid] = INFINITY; qcnt[tid] = 0; }
  if (tid == 0) more = 0;

  const float* xb = x + (size_t)b * Cc * Nn;

  // stage Xn once (scaled by -2): 1024 float4, lane-contiguous
#pragma unroll
  for (int i = 0; i < 4; i++) {
    int f = i * 256 + tid;                // float4 index in [0,1024)
    int c = f >> 4;
    int m = (f & 15) << 2;
    float4 v = *(const float4*)(xb + (size_t)c * Nn + n0 + m);
    v.x *= -2.f; v.y *= -2.f; v.z *= -2.f; v.w *= -2.f;
    *(float4*)&Xn[c][m] = v;
  }
  __syncthreads();

  float acc[4][8];

  for (int m0 = 0; m0 < Nn; m0 += 128) {
    // stage Xm: 2048 float4, lane-contiguous
#pragma unroll
    for (int i = 0; i < 8; i++) {
      int f = i * 256 + tid;
      int c = f >> 5;
      int m = (f & 31) << 2;
      *(float4*)&Xm[c][m] = *(const float4*)(xb + (size_t)c * Nn + m0 + m);
    }
    if (tid < 32) ((float4*)sqs)[tid] = ((const float4*)(sqv + b * Nn + m0))[tid];
    __syncthreads();

#pragma unroll
    for (int ii = 0; ii < 4; ii++)
#pragma unroll
      for (int jj = 0; jj < 8; jj++) acc[ii][jj] = 0.0f;

#pragma unroll 8
    for (int c = 0; c < Cc; c++) {
      float4 av = *(const float4*)&Xn[c][ty << 2];
      float4 b0 = *(const float4*)&Xm[c][tx << 2];
      float4 b1 = *(const float4*)&Xm[c][64 + (tx << 2)];
      float aa[4] = {av.x, av.y, av.z, av.w};
      float bb[8] = {b0.x, b0.y, b0.z, b0.w, b1.x, b1.y, b1.z, b1.w};
#pragma unroll
      for (int ii = 0; ii < 4; ii++)
#pragma unroll
        for (int jj = 0; jj < 8; jj++)
          acc[ii][jj] = fmaf(aa[ii], bb[jj], acc[ii][jj]);
    }

    // keys = sq[m] - 2*dot (row-constant sq[n] dropped; order-preserving)
    {
      float4 s0 = *(const float4*)&sqs[tx << 2];
      float4 s1 = *(const float4*)&sqs[64 + (tx << 2)];
      float sv[8] = {s0.x, s0.y, s0.z, s0.w, s1.x, s1.y, s1.z, s1.w};
#pragma unroll
      for (int ii = 0; ii < 4; ii++)
#pragma unroll
        for (int jj = 0; jj < 8; jj++) acc[ii][jj] += sv[jj];
    }

    // build pend bitmask of below-threshold candidates
    unsigned pend = 0;
    {
      float tloc[4];
#pragma unroll
      for (int ii = 0; ii < 4; ii++) tloc[ii] = thrS[(ty << 2) + ii];
#pragma unroll
      for (int ii = 0; ii < 4; ii++)
#pragma unroll
        for (int jj = 0; jj < 8; jj++)
          if (acc[ii][jj] < tloc[ii]) pend |= 1u << (ii * 8 + jj);
    }

    // push / drain (retry only on queue overflow; steady state = 1 pass)
    for (;;) {
      if (pend) {
#pragma unroll
        for (int ii = 0; ii < 4; ii++) {
          int row = (ty << 2) + ii;
#pragma unroll
          for (int jj = 0; jj < 8; jj++) {
            unsigned bit = 1u << (ii * 8 + jj);
            if (pend & bit) {
              int p = atomicAdd(&qcnt[row], 1);
              if (p < QCAP) {
                qk[row][p] = acc[ii][jj];
                int col = m0 + ((jj < 4) ? (tx << 2) + jj : 64 + (tx << 2) + (jj - 4));
                qm[row][p] = (unsigned short)col;
                pend &= ~bit;
              } else {
                more = 1;                      // benign racy flag
              }
            }
          }
        }
      }
      __syncthreads();                         // A: queues + 'more' visible

      if (tid < 64) {                          // drain: 64 rows in parallel
        int cn = qcnt[tid];
        if (cn > QCAP) cn = QCAP;
        for (int p = 0; p < cn; p++) {
          float kv = qk[tid][p];
          if (kv < hthr) {
            int mvi = (int)qm[tid][p];
            float mx = -INFINITY, mx2 = -INFINITY;
            int sl = 0;
#pragma unroll
            for (int kk = 0; kk < Kk; kk++) {
              float v = hk[kk];
              if (v > mx) { mx2 = mx; mx = v; sl = kk; }
              else if (v > mx2) mx2 = v;
            }
#pragma unroll
            for (int kk = 0; kk < Kk; kk++) {
              bool hit = (kk == sl);
              hk[kk] = hit ? kv : hk[kk];
              hix[kk] = hit ? mvi : hix[kk];
            }
            hthr = fmaxf(mx2, kv);
          }
        }
        qcnt[tid] = 0;
        thrS[tid] = hthr;
      }
      int go = more;                           // written only in push phase
      __syncthreads();                         // B: drain results visible
      if (!go) break;
      if (tid == 0) more = 0;
      // refilter surviving bits against the tightened thresholds
      {
        float tloc[4];
#pragma unroll
        for (int ii = 0; ii < 4; ii++) tloc[ii] = thrS[(ty << 2) + ii];
#pragma unroll
        for (int ii = 0; ii < 4; ii++)
#pragma unroll
          for (int jj = 0; jj < 8; jj++) {
            unsigned bit = 1u << (ii * 8 + jj);
            if ((pend & bit) && acc[ii][jj] >= tloc[ii]) pend &= ~bit;
          }
      }
      __syncthreads();                         // C: 'more' reset before pushes
    }
    __syncthreads();
  }

  // final write: handler lane owns row tid's list
  if (tid < 64) {
    size_t base = ((size_t)b * Nn + n0 + tid) * Kk;
#pragma unroll
    for (int kk = 0; kk < Kk; kk++) idxout[base + kk] = hix[kk];
  }
}

// ---------------------------------------------------------------- k_stats
__global__ __launch_bounds__(256) void k_stats(const float* __restrict__ y1,
                                               const float* __restrict__ z,
                                               const int* __restrict__ idxp,
                                               float* __restrict__ stats) {
  __shared__ float rs[4][64];
  __shared__ float rq[4][64];
  int tid = threadIdx.x;
  int o = tid & 63, g = tid >> 6;
  int b = blockIdx.x >> 6;
  int n0 = (blockIdx.x & 63) << 6;
  const float* y1b = y1 + (size_t)b * Nn * 64;
  float s = 0.f, ss = 0.f;
  for (int t = 0; t < 16; t++) {
    int n = n0 + g + t * 4;
    size_t base = (size_t)b * Nn + n;
    float zv = z[base * 64 + o];
    const int* ip = idxp + base * Kk;
#pragma unroll
    for (int k = 0; k < Kk; k++) {
      int j = ip[k];
      float hv = y1b[(size_t)j * 64 + o] + zv;
      s += hv;
      ss = fmaf(hv, hv, ss);
    }
  }
  rs[g][o] = s;
  rq[g][o] = ss;
  __syncthreads();
  if (tid < 64) {
    float a = rs[0][tid] + rs[1][tid] + rs[2][tid] + rs[3][tid];
    float q = rq[0][tid] + rq[1][tid] + rq[2][tid] + rq[3][tid];
    atomicAdd(&stats[tid], a);
    atomicAdd(&stats[64 + tid], q);
  }
}

// ---------------------------------------------------------------- k_out
__global__ __launch_bounds__(256) void k_out(const float* __restrict__ y1,
                                             const float* __restrict__ z,
                                             const int* __restrict__ idxp,
                                             const float* __restrict__ stats,
                                             const float* __restrict__ gamma,
                                             const float* __restrict__ beta,
                                             float* __restrict__ out) {
  __shared__ float T[64][65];
  int tid = threadIdx.x;
  int lane = tid & 63;
  int w = tid >> 6;
  int b = blockIdx.x >> 6;
  int n0 = (blockIdx.x & 63) << 6;
  int o = lane;
  const float inv = 1.0f / (float)NTOT;
  float mean = stats[o] * inv;
  float var = fmaf(-mean, mean, stats[64 + o] * inv);
  float sc = gamma[o] * rsqrtf(var + 1e-5f);
  float bi = fmaf(-mean, sc, beta[o]);
  const float* y1b = y1 + (size_t)b * Nn * 64;
  for (int t = 0; t < 16; t++) {
    int nl = w + t * 4;
    size_t base = (size_t)b * Nn + n0 + nl;
    float zv = z[base * 64 + o];
    const int* ip = idxp + base * Kk;
    float mv = -INFINITY;
#pragma unroll
    for (int k = 0; k < Kk; k++) {
      int j = ip[k];
      float hv = y1b[(size_t)j * 64 + o] + zv;
      float hn = fmaf(hv, sc, bi);
      float a = (hn >= 0.f) ? hn : 0.2f * hn;
      mv = fmaxf(mv, a);
    }
    T[o][nl] = mv;
  }
  __syncthreads();
  for (int t = 0; t < 16; t++) {
    int oo = w * 16 + t;
    out[((size_t)b * Oo + oo) * Nn + n0 + lane] = T[oo][lane];
  }
}

// ---------------------------------------------------------------- launch
extern "C" void kernel_launch(void* const* d_in, const int* in_sizes, int n_in,
                              void* d_out, int out_size, void* d_ws, size_t ws_size,
                              hipStream_t stream) {
  const float* x = (const float*)d_in[0];
  const float* W = (const float*)d_in[1];
  const float* gamma = (const float*)d_in[2];
  const float* beta = (const float*)d_in[3];
  // d_in[4] is k (=20), baked in as Kk.

  char* ws = (char*)d_ws;
  float* y1 = (float*)ws;
  float* z = (float*)(ws + 8388608);
  float* sq = (float*)(ws + 16777216);
  float* stats = (float*)(ws + 16908288);
  int* idx = (int*)(ws + 16908800);
  float* out = (float*)d_out;

  hipMemsetAsync(stats, 0, 128 * sizeof(float), stream);
  k_sq<<<(Bn * Nn) / 256, 256, 0, stream>>>(x, sq);
  k_y1z<<<Bn * (Nn / 64), 256, 0, stream>>>(x, W, y1, z);
  k_knn<<<Bn * (Nn / 64), 256, 0, stream>>>(x, sq, idx);
  k_stats<<<Bn * (Nn / 64), 256, 0, stream>>>(y1, z, idx, stats);
  k_out<<<Bn * (Nn / 64), 256, 0, stream>>>(y1, z, idx, stats, gamma, beta, out);
}

// Round 5
// 645.016 us; speedup vs baseline: 5.1866x; 1.2632x over previous
//
#include <hip/hip_runtime.h>
#include <math.h>

// Problem constants (setup_inputs): B=8, C=64, N=4096, O=64, K=20
#define Bn 8
#define Cc 64
#define Nn 4096
#define Oo 64
#define Kk 20
#define QCAP 32              // per-row candidate queue capacity per tile
#define NTOT (Bn*Nn*Kk)      // 655360 elements per BN channel

typedef __attribute__((ext_vector_type(8))) short short8;
typedef __attribute__((ext_vector_type(4))) float f32x4;

__device__ __forceinline__ unsigned bf16_rn(float v) {
  unsigned u = __float_as_uint(v);
  return (u + 0x7FFFu + ((u >> 16) & 1)) >> 16;     // RN-even
}

// ---------------------------------------------------------------- k_sq
__global__ __launch_bounds__(256) void k_sq(const float* __restrict__ x,
                                            float* __restrict__ sqv) {
  int g = blockIdx.x * 256 + threadIdx.x;          // g in [0, B*N)
  int b = g >> 12;
  int n = g & (Nn - 1);
  const float* xp = x + (size_t)b * Cc * Nn + n;
  float s = 0.f;
#pragma unroll
  for (int c = 0; c < Cc; c++) { float v = xp[(size_t)c * Nn]; s = fmaf(v, v, s); }
  sqv[g] = s;
}

// ---------------------------------------------------------------- k_split
// x fp32 [b][c][n] -> 3-term bf16 split, transposed to [b][n][c]:
//   h = RN(x); m = RN(x-h); l = RN(x-h-m)   (x-h, x-h-m exact in fp32)
// Residual after 3 terms <= 2^-24|x| -> fp32-class kNN key accuracy.
__global__ __launch_bounds__(256) void k_split(const float* __restrict__ x,
                                               unsigned short* __restrict__ xhi,
                                               unsigned short* __restrict__ xmid,
                                               unsigned short* __restrict__ xlo) {
  __shared__ float xs[64][65];
  int tid = threadIdx.x;
  int b = blockIdx.x & 7;
  int n0 = (blockIdx.x >> 3) << 6;
  for (int i = 0; i < 16; i++) {
    int c = i * 4 + (tid >> 6);
    int n = tid & 63;
    xs[c][n] = x[((size_t)b * Cc + c) * Nn + n0 + n];
  }
  __syncthreads();
  for (int i = 0; i < 16; i++) {
    int n = i * 4 + (tid >> 6);
    int c = tid & 63;
    float v = xs[c][n];
    unsigned hb = bf16_rn(v);
    float hf = __uint_as_float(hb << 16);
    float r1 = v - hf;                                       // exact
    unsigned mb = bf16_rn(r1);
    float mf = __uint_as_float(mb << 16);
    float r2 = r1 - mf;                                      // exact
    unsigned lb = bf16_rn(r2);
    size_t o = ((size_t)(b << 12) + n0 + n) * 64 + c;
    xhi[o] = (unsigned short)hb;
    xmid[o] = (unsigned short)mb;
    xlo[o] = (unsigned short)lb;
  }
}

// ---------------------------------------------------------------- k_y1z
__global__ __launch_bounds__(256) void k_y1z(const float* __restrict__ x,
                                             const float* __restrict__ Wm,
                                             float* __restrict__ y1,
                                             float* __restrict__ z) {
  __shared__ float xs[64][64];
  __shared__ float Wl[64][129];
  int tid = threadIdx.x;
  int b = blockIdx.x & 7;
  int n0 = (blockIdx.x >> 3) << 6;
  for (int i = tid; i < 64 * 128; i += 256) Wl[i >> 7][i & 127] = Wm[i];
  for (int i = 0; i < 16; i++) {
    int c = i * 4 + (tid >> 6);
    int n = tid & 63;
    xs[c][n] = x[((size_t)b * Cc + c) * Nn + n0 + n];
  }
  __syncthreads();
  int o = tid & 63, ng = tid >> 6;
  for (int p = 0; p < 16; p++) {
    int n = ng + p * 4;
    float a1 = 0.f, a2 = 0.f;
#pragma unroll 8
    for (int c = 0; c < 64; c++) {
      float xv = xs[c][n];
      a1 = fmaf(xv, Wl[o][c], a1);
      a2 = fmaf(xv, Wl[o][64 + c], a2);
    }
    size_t off = ((size_t)b * Nn + n0 + n) * 64 + o;
    y1[off] = a1;
    z[off] = a2 - a1;
  }
}

// ---------------------------------------------------------------- k_knn (v5)
// 3-term split-bf16 MFMA Gram: dot = mm + hl + lh + hm + mh + hh (smallest
// first into fp32 acc; dropped ml/ll are 2^-24-level). 64 query rows/block;
// A-frags (h/m/l) in registers; B tile 3 layers bf16 [m][c] stride 72 (2-way,
// free). C-layout col=lane&15 (candidate), row=quad*4+reg (query).
// Top-k: padded LDS queues + 64 register-resident handler lists (round 3/4).
// LDS ~69KB -> 2 blocks/CU.
__global__ __launch_bounds__(256, 2) void k_knn(const unsigned short* __restrict__ xhi,
                                                const unsigned short* __restrict__ xmid,
                                                const unsigned short* __restrict__ xlo,
                                                const float* __restrict__ sqv,
                                                int* __restrict__ idxout) {
  __shared__ alignas(16) short Bs[3][128][72];   // [h/m/l][m][c], padded
  __shared__ float thrS[64];
  __shared__ float sqs[128];
  __shared__ float qk[64][33];                   // stride 33 -> 2-way handler reads
  __shared__ unsigned short qm[64][34];          // stride 34 shorts
  __shared__ int qcnt[64];
  __shared__ int more;

  const int tid = threadIdx.x;
  const int lane = tid & 63;
  const int w = tid >> 6;
  const int b = blockIdx.x & 7;                  // XCD swizzle: batch per XCD
  const int n0 = (blockIdx.x >> 3) << 6;
  const int lm = lane & 15;                      // candidate col / A row
  const int q = lane >> 4;                       // quad: k-subrange selector

  // handler state (row = tid for tid<64)
  float hk[Kk];
  int hix[Kk];
  float hthr = INFINITY;
#pragma unroll
  for (int kk = 0; kk < Kk; kk++) { hk[kk] = INFINITY; hix[kk] = 0; }

  if (tid < 64) { thrS[tid] = INFINITY; qcnt[tid] = 0; }
  if (tid == 0) more = 0;

  // A fragments: wave w owns query rows n0+w*16 .. +15; loaded once.
  const size_t arow = ((size_t)(b << 12) + n0 + w * 16 + lm) * 64;
  short8 ah0 = *(const short8*)&xhi[arow + q * 8];
  short8 ah1 = *(const short8*)&xhi[arow + 32 + q * 8];
  short8 am0 = *(const short8*)&xmid[arow + q * 8];
  short8 am1 = *(const short8*)&xmid[arow + 32 + q * 8];
  short8 al0 = *(const short8*)&xlo[arow + q * 8];
  short8 al1 = *(const short8*)&xlo[arow + 32 + q * 8];

  __syncthreads();   // thrS/qcnt init visible

  f32x4 acc[8];

  for (int m0 = 0; m0 < Nn; m0 += 128) {
    // stage B tile: 3 layers x 128 rows x 8 chunks of short8, coalesced
#pragma unroll
    for (int i = 0; i < 12; i++) {
      int f = i * 256 + tid;                      // [0,3072); layer uniform/i
      int layer = f >> 10;
      int r = (f >> 3) & 127;
      int qq = f & 7;
      const unsigned short* src = (layer == 0) ? xhi : (layer == 1) ? xmid : xlo;
      short8 v = *(const short8*)&src[((size_t)(b << 12) + m0 + r) * 64 + qq * 8];
      *(short8*)&Bs[layer][r][qq * 8] = v;
    }
    if (tid < 32) ((float4*)sqs)[tid] = ((const float4*)(sqv + b * Nn + m0))[tid];
    __syncthreads();

#pragma unroll
    for (int g = 0; g < 8; g++) acc[g] = (f32x4){0.f, 0.f, 0.f, 0.f};

#pragma unroll
    for (int g = 0; g < 8; g++) {
      const int mr = g * 16 + lm;
      short8 bh0 = *(const short8*)&Bs[0][mr][q * 8];
      short8 bh1 = *(const short8*)&Bs[0][mr][32 + q * 8];
      short8 bm0 = *(const short8*)&Bs[1][mr][q * 8];
      short8 bm1 = *(const short8*)&Bs[1][mr][32 + q * 8];
      short8 bl0 = *(const short8*)&Bs[2][mr][q * 8];
      short8 bl1 = *(const short8*)&Bs[2][mr][32 + q * 8];
      f32x4 a = acc[g];
      a = __builtin_amdgcn_mfma_f32_16x16x32_bf16(am0, bm0, a, 0, 0, 0);  // mm
      a = __builtin_amdgcn_mfma_f32_16x16x32_bf16(am1, bm1, a, 0, 0, 0);
      a = __builtin_amdgcn_mfma_f32_16x16x32_bf16(ah0, bl0, a, 0, 0, 0);  // hl
      a = __builtin_amdgcn_mfma_f32_16x16x32_bf16(ah1, bl1, a, 0, 0, 0);
      a = __builtin_amdgcn_mfma_f32_16x16x32_bf16(al0, bh0, a, 0, 0, 0);  // lh
      a = __builtin_amdgcn_mfma_f32_16x16x32_bf16(al1, bh1, a, 0, 0, 0);
      a = __builtin_amdgcn_mfma_f32_16x16x32_bf16(ah0, bm0, a, 0, 0, 0);  // hm
      a = __builtin_amdgcn_mfma_f32_16x16x32_bf16(ah1, bm1, a, 0, 0, 0);
      a = __builtin_amdgcn_mfma_f32_16x16x32_bf16(am0, bh0, a, 0, 0, 0);  // mh
      a = __builtin_amdgcn_mfma_f32_16x16x32_bf16(am1, bh1, a, 0, 0, 0);
      a = __builtin_amdgcn_mfma_f32_16x16x32_bf16(ah0, bh0, a, 0, 0, 0);  // hh
      a = __builtin_amdgcn_mfma_f32_16x16x32_bf16(ah1, bh1, a, 0, 0, 0);
      acc[g] = a;
    }

    // keys = sq[m] - 2*dot; lane's 32 candidates = 8 col-groups x 4 rows
    unsigned pend = 0;
    {
      float tl[4];
#pragma unroll
      for (int r = 0; r < 4; r++) tl[r] = thrS[w * 16 + q * 4 + r];
#pragma unroll
      for (int g = 0; g < 8; g++) {
        float sv = sqs[g * 16 + lm];
#pragma unroll
        for (int r = 0; r < 4; r++) {
          float key = fmaf(-2.f, acc[g][r], sv);
          acc[g][r] = key;
          if (key < tl[r]) pend |= 1u << (g * 4 + r);
        }
      }
    }

    // push / drain (retry only on queue overflow; steady state = 1 pass)
    for (;;) {
      if (pend) {
#pragma unroll
        for (int g = 0; g < 8; g++) {
#pragma unroll
          for (int r = 0; r < 4; r++) {
            unsigned bit = 1u << (g * 4 + r);
            if (pend & bit) {
              int row = w * 16 + q * 4 + r;
              int p = atomicAdd(&qcnt[row], 1);
              if (p < QCAP) {
                qk[row][p] = acc[g][r];
                qm[row][p] = (unsigned short)(m0 + g * 16 + lm);
                pend &= ~bit;
              } else {
                more = 1;                      // benign racy flag
              }
            }
          }
        }
      }
      __syncthreads();                         // A: queues + 'more' visible

      if (tid < 64) {                          // drain: 64 rows in parallel
        int cn = qcnt[tid];
        if (cn > QCAP) cn = QCAP;
        for (int p = 0; p < cn; p++) {
          float kv = qk[tid][p];
          if (kv < hthr) {
            int mvi = (int)qm[tid][p];
            float mx = -INFINITY, mx2 = -INFINITY;
            int sl = 0;
#pragma unroll
            for (int kk = 0; kk < Kk; kk++) {
              float v = hk[kk];
              if (v > mx) { mx2 = mx; mx = v; sl = kk; }
              else if (v > mx2) mx2 = v;
            }
#pragma unroll
            for (int kk = 0; kk < Kk; kk++) {
              bool hit = (kk == sl);
              hk[kk] = hit ? kv : hk[kk];
              hix[kk] = hit ? mvi : hix[kk];
            }
            hthr = fmaxf(mx2, kv);
          }
        }
        qcnt[tid] = 0;
        thrS[tid] = hthr;
      }
      int go = more;                           // written only in push phase
      __syncthreads();                         // B: drain results visible
      if (!go) break;
      if (tid == 0) more = 0;
      // refilter surviving bits against the tightened thresholds
      {
        float tl[4];
#pragma unroll
        for (int r = 0; r < 4; r++) tl[r] = thrS[w * 16 + q * 4 + r];
#pragma unroll
        for (int g = 0; g < 8; g++)
#pragma unroll
          for (int r = 0; r < 4; r++) {
            unsigned bit = 1u << (g * 4 + r);
            if ((pend & bit) && acc[g][r] >= tl[r]) pend &= ~bit;
          }
      }
      __syncthreads();                         // C: 'more' reset before pushes
    }
  }

  // final write: handler lane owns row tid's list
  if (tid < 64) {
    size_t base = ((size_t)b * Nn + n0 + tid) * Kk;
#pragma unroll
    for (int kk = 0; kk < Kk; kk++) idxout[base + kk] = hix[kk];
  }
}

// ---------------------------------------------------------------- k_stats
__global__ __launch_bounds__(256) void k_stats(const float* __restrict__ y1,
                                               const float* __restrict__ z,
                                               const int* __restrict__ idxp,
                                               float* __restrict__ stats) {
  __shared__ float rs[4][64];
  __shared__ float rq[4][64];
  int tid = threadIdx.x;
  int o = tid & 63, g = tid >> 6;
  int b = blockIdx.x & 7;                       // XCD swizzle
  int n0 = (blockIdx.x >> 3) << 6;
  const float* y1b = y1 + (size_t)b * Nn * 64;
  float s = 0.f, ss = 0.f;
  for (int t = 0; t < 16; t++) {
    int n = n0 + g + t * 4;
    size_t base = (size_t)b * Nn + n;
    float zv = z[base * 64 + o];
    const int* ip = idxp + base * Kk;
#pragma unroll
    for (int k = 0; k < Kk; k++) {
      int j = ip[k];
      float hv = y1b[(size_t)j * 64 + o] + zv;
      s += hv;
      ss = fmaf(hv, hv, ss);
    }
  }
  rs[g][o] = s;
  rq[g][o] = ss;
  __syncthreads();
  if (tid < 64) {
    float a = rs[0][tid] + rs[1][tid] + rs[2][tid] + rs[3][tid];
    float qq = rq[0][tid] + rq[1][tid] + rq[2][tid] + rq[3][tid];
    atomicAdd(&stats[tid], a);
    atomicAdd(&stats[64 + tid], qq);
  }
}

// ---------------------------------------------------------------- k_out
__global__ __launch_bounds__(256) void k_out(const float* __restrict__ y1,
                                             const float* __restrict__ z,
                                             const int* __restrict__ idxp,
                                             const float* __restrict__ stats,
                                             const float* __restrict__ gamma,
                                             const float* __restrict__ beta,
                                             float* __restrict__ out) {
  __shared__ float T[64][65];
  int tid = threadIdx.x;
  int lane = tid & 63;
  int w = tid >> 6;
  int b = blockIdx.x & 7;                       // XCD swizzle
  int n0 = (blockIdx.x >> 3) << 6;
  int o = lane;
  const float inv = 1.0f / (float)NTOT;
  float mean = stats[o] * inv;
  float var = fmaf(-mean, mean, stats[64 + o] * inv);
  float sc = gamma[o] * rsqrtf(var + 1e-5f);
  float bi = fmaf(-mean, sc, beta[o]);
  const float* y1b = y1 + (size_t)b * Nn * 64;
  for (int t = 0; t < 16; t++) {
    int nl = w + t * 4;
    size_t base = (size_t)b * Nn + n0 + nl;
    float zv = z[base * 64 + o];
    const int* ip = idxp + base * Kk;
    float mv = -INFINITY;
#pragma unroll
    for (int k = 0; k < Kk; k++) {
      int j = ip[k];
      float hv = y1b[(size_t)j * 64 + o] + zv;
      float hn = fmaf(hv, sc, bi);
      float a = (hn >= 0.f) ? hn : 0.2f * hn;
      mv = fmaxf(mv, a);
    }
    T[o][nl] = mv;
  }
  __syncthreads();
  for (int t = 0; t < 16; t++) {
    int oo = w * 16 + t;
    out[((size_t)b * Oo + oo) * Nn + n0 + lane] = T[oo][lane];
  }
}

// ---------------------------------------------------------------- launch
extern "C" void kernel_launch(void* const* d_in, const int* in_sizes, int n_in,
                              void* d_out, int out_size, void* d_ws, size_t ws_size,
                              hipStream_t stream) {
  const float* x = (const float*)d_in[0];
  const float* W = (const float*)d_in[1];
  const float* gamma = (const float*)d_in[2];
  const float* beta = (const float*)d_in[3];
  // d_in[4] is k (=20), baked in as Kk.

  // workspace layout (bytes):
  //   xhi  : [0,        4194304)  bf16 [b][n][c]  \  dead after k_knn;
  //   xmid : [4194304,  8388608)  bf16 [b][n][c]   } y1 overlays [0,8M),
  //   xlo  : [8388608, 12582912)  bf16 [b][n][c]  /  z overlays [8M,16M)
  //   y1   : [0,        8388608)  B*N*O fp32  (written by k_y1z, after k_knn)
  //   z    : [8388608, 16777216)  B*N*O fp32  (written by k_y1z, after k_knn)
  //   sq   : [16777216,16908288)  B*N fp32
  //   stats: [16908288,16908800)  128 fp32
  //   idx  : [16908800,19530240)  B*N*K int32
  char* ws = (char*)d_ws;
  unsigned short* xhi = (unsigned short*)ws;
  unsigned short* xmid = (unsigned short*)(ws + 4194304);
  unsigned short* xlo = (unsigned short*)(ws + 8388608);
  float* y1 = (float*)ws;
  float* z = (float*)(ws + 8388608);
  float* sq = (float*)(ws + 16777216);
  float* stats = (float*)(ws + 16908288);
  int* idx = (int*)(ws + 16908800);
  float* out = (float*)d_out;

  hipMemsetAsync(stats, 0, 128 * sizeof(float), stream);
  k_split<<<Bn * (Nn / 64), 256, 0, stream>>>(x, xhi, xmid, xlo);
  k_sq<<<(Bn * Nn) / 256, 256, 0, stream>>>(x, sq);
  k_knn<<<Bn * (Nn / 64), 256, 0, stream>>>(xhi, xmid, xlo, sq, idx);
  k_y1z<<<Bn * (Nn / 64), 256, 0, stream>>>(x, W, y1, z);
  k_stats<<<Bn * (Nn / 64), 256, 0, stream>>>(y1, z, idx, stats);
  k_out<<<Bn * (Nn / 64), 256, 0, stream>>>(y1, z, idx, stats, gamma, beta, out);
}

// Round 6
// 625.818 us; speedup vs baseline: 5.3457x; 1.0307x over previous
//
#include <hip/hip_runtime.h>
#include <math.h>

// Problem constants (setup_inputs): B=8, C=64, N=4096, O=64, K=20
#define Bn 8
#define Cc 64
#define Nn 4096
#define Oo 64
#define Kk 20
#define QCAP 32              // per-row candidate queue capacity per tile
#define NTOT (Bn*Nn*Kk)      // 655360 elements per BN channel

typedef __attribute__((ext_vector_type(8))) short short8;
typedef __attribute__((ext_vector_type(4))) float f32x4;

__device__ __forceinline__ unsigned bf16_rn(float v) {
  unsigned u = __float_as_uint(v);
  return (u + 0x7FFFu + ((u >> 16) & 1)) >> 16;     // RN-even
}

// ---------------------------------------------------------------- k_sq
__global__ __launch_bounds__(256) void k_sq(const float* __restrict__ x,
                                            float* __restrict__ sqv) {
  int g = blockIdx.x * 256 + threadIdx.x;          // g in [0, B*N)
  int b = g >> 12;
  int n = g & (Nn - 1);
  const float* xp = x + (size_t)b * Cc * Nn + n;
  float s = 0.f;
#pragma unroll
  for (int c = 0; c < Cc; c++) { float v = xp[(size_t)c * Nn]; s = fmaf(v, v, s); }
  sqv[g] = s;
}

// ---------------------------------------------------------------- k_split
// x fp32 [b][c][n] -> 3-term bf16 split, transposed to [b][n][c]:
//   h = RN(x); m = RN(x-h); l = RN(x-h-m)   (x-h, x-h-m exact in fp32)
__global__ __launch_bounds__(256) void k_split(const float* __restrict__ x,
                                               unsigned short* __restrict__ xhi,
                                               unsigned short* __restrict__ xmid,
                                               unsigned short* __restrict__ xlo) {
  __shared__ float xs[64][65];
  int tid = threadIdx.x;
  int b = blockIdx.x & 7;
  int n0 = (blockIdx.x >> 3) << 6;
  for (int i = 0; i < 16; i++) {
    int c = i * 4 + (tid >> 6);
    int n = tid & 63;
    xs[c][n] = x[((size_t)b * Cc + c) * Nn + n0 + n];
  }
  __syncthreads();
  for (int i = 0; i < 16; i++) {
    int n = i * 4 + (tid >> 6);
    int c = tid & 63;
    float v = xs[c][n];
    unsigned hb = bf16_rn(v);
    float hf = __uint_as_float(hb << 16);
    float r1 = v - hf;                                       // exact
    unsigned mb = bf16_rn(r1);
    float mf = __uint_as_float(mb << 16);
    float r2 = r1 - mf;                                      // exact
    unsigned lb = bf16_rn(r2);
    size_t o = ((size_t)(b << 12) + n0 + n) * 64 + c;
    xhi[o] = (unsigned short)hb;
    xmid[o] = (unsigned short)mb;
    xlo[o] = (unsigned short)lb;
  }
}

// ---------------------------------------------------------------- k_y1z
__global__ __launch_bounds__(256) void k_y1z(const float* __restrict__ x,
                                             const float* __restrict__ Wm,
                                             float* __restrict__ y1,
                                             float* __restrict__ z) {
  __shared__ float xs[64][64];
  __shared__ float Wl[64][129];
  int tid = threadIdx.x;
  int b = blockIdx.x & 7;
  int n0 = (blockIdx.x >> 3) << 6;
  for (int i = tid; i < 64 * 128; i += 256) Wl[i >> 7][i & 127] = Wm[i];
  for (int i = 0; i < 16; i++) {
    int c = i * 4 + (tid >> 6);
    int n = tid & 63;
    xs[c][n] = x[((size_t)b * Cc + c) * Nn + n0 + n];
  }
  __syncthreads();
  int o = tid & 63, ng = tid >> 6;
  for (int p = 0; p < 16; p++) {
    int n = ng + p * 4;
    float a1 = 0.f, a2 = 0.f;
#pragma unroll 8
    for (int c = 0; c < 64; c++) {
      float xv = xs[c][n];
      a1 = fmaf(xv, Wl[o][c], a1);
      a2 = fmaf(xv, Wl[o][64 + c], a2);
    }
    size_t off = ((size_t)b * Nn + n0 + n) * 64 + o;
    y1[off] = a1;
    z[off] = a2 - a1;
  }
}

// ---------------------------------------------------------------- k_knn (v6)
// 3-term split-bf16 MFMA Gram (round 5) + WAVE-PRIVATE top-k:
// candidate row w*16+q*4+r is always produced by wave w, so queues, thresholds
// and handlers are per-wave-private. DS ops within a wave complete in order ->
// the entire push/drain loop needs NO __syncthreads (round 5 spent ~80% of
// time with 3 of 4 waves parked at drain barriers). Only 2 barriers/tile
// remain (B staging). Handlers: lanes 0-15 of each wave drain their 16 rows
// concurrently; queue reads chunked (float4/ushort4 -> 1 LDS latency / 4 pops).
// Queue strides 36 (16B/8B-aligned rows, <=2-way banks). LDS ~70KB -> 2/CU.
__global__ __launch_bounds__(256, 2) void k_knn(const unsigned short* __restrict__ xhi,
                                                const unsigned short* __restrict__ xmid,
                                                const unsigned short* __restrict__ xlo,
                                                const float* __restrict__ sqv,
                                                int* __restrict__ idxout) {
  __shared__ alignas(16) short Bs[3][128][72];   // [h/m/l][m][c], padded
  __shared__ float thrS[64];
  __shared__ float sqs[128];
  __shared__ alignas(16) float qk[64][36];       // stride 36 floats (144B rows)
  __shared__ alignas(8) unsigned short qm[64][36];
  __shared__ int qcnt[64];

  const int tid = threadIdx.x;
  const int lane = tid & 63;
  const int w = tid >> 6;
  const int b = blockIdx.x & 7;                  // XCD swizzle: batch per XCD
  const int n0 = (blockIdx.x >> 3) << 6;
  const int lm = lane & 15;                      // candidate col / A row
  const int q = lane >> 4;                       // quad: k-subrange selector
  const int myrow = w * 16 + lm;                 // row drained by this lane
  const bool handler = (lane < 16);

  // handler state (meaningful on lanes 0-15 of each wave)
  float hk[Kk];
  int hix[Kk];
  float hthr = INFINITY;
#pragma unroll
  for (int kk = 0; kk < Kk; kk++) { hk[kk] = INFINITY; hix[kk] = 0; }

  if (handler) { thrS[myrow] = INFINITY; qcnt[myrow] = 0; }  // wave-private init

  // A fragments: wave w owns query rows n0+w*16 .. +15; loaded once.
  const size_t arow = ((size_t)(b << 12) + n0 + w * 16 + lm) * 64;
  short8 ah0 = *(const short8*)&xhi[arow + q * 8];
  short8 ah1 = *(const short8*)&xhi[arow + 32 + q * 8];
  short8 am0 = *(const short8*)&xmid[arow + q * 8];
  short8 am1 = *(const short8*)&xmid[arow + 32 + q * 8];
  short8 al0 = *(const short8*)&xlo[arow + q * 8];
  short8 al1 = *(const short8*)&xlo[arow + 32 + q * 8];

  f32x4 acc[8];

  for (int m0 = 0; m0 < Nn; m0 += 128) {
    __syncthreads();                              // all waves done reading Bs
    // stage B tile: 3 layers x 128 rows x 8 chunks of short8, coalesced
#pragma unroll
    for (int i = 0; i < 12; i++) {
      int f = i * 256 + tid;                      // [0,3072); layer uniform/i
      int layer = f >> 10;
      int r = (f >> 3) & 127;
      int qq = f & 7;
      const unsigned short* src = (layer == 0) ? xhi : (layer == 1) ? xmid : xlo;
      short8 v = *(const short8*)&src[((size_t)(b << 12) + m0 + r) * 64 + qq * 8];
      *(short8*)&Bs[layer][r][qq * 8] = v;
    }
    if (tid < 32) ((float4*)sqs)[tid] = ((const float4*)(sqv + b * Nn + m0))[tid];
    __syncthreads();                              // staging visible

#pragma unroll
    for (int g = 0; g < 8; g++) acc[g] = (f32x4){0.f, 0.f, 0.f, 0.f};

#pragma unroll
    for (int g = 0; g < 8; g++) {
      const int mr = g * 16 + lm;
      short8 bh0 = *(const short8*)&Bs[0][mr][q * 8];
      short8 bh1 = *(const short8*)&Bs[0][mr][32 + q * 8];
      short8 bm0 = *(const short8*)&Bs[1][mr][q * 8];
      short8 bm1 = *(const short8*)&Bs[1][mr][32 + q * 8];
      short8 bl0 = *(const short8*)&Bs[2][mr][q * 8];
      short8 bl1 = *(const short8*)&Bs[2][mr][32 + q * 8];
      f32x4 a = acc[g];
      a = __builtin_amdgcn_mfma_f32_16x16x32_bf16(am0, bm0, a, 0, 0, 0);  // mm
      a = __builtin_amdgcn_mfma_f32_16x16x32_bf16(am1, bm1, a, 0, 0, 0);
      a = __builtin_amdgcn_mfma_f32_16x16x32_bf16(ah0, bl0, a, 0, 0, 0);  // hl
      a = __builtin_amdgcn_mfma_f32_16x16x32_bf16(ah1, bl1, a, 0, 0, 0);
      a = __builtin_amdgcn_mfma_f32_16x16x32_bf16(al0, bh0, a, 0, 0, 0);  // lh
      a = __builtin_amdgcn_mfma_f32_16x16x32_bf16(al1, bh1, a, 0, 0, 0);
      a = __builtin_amdgcn_mfma_f32_16x16x32_bf16(ah0, bm0, a, 0, 0, 0);  // hm
      a = __builtin_amdgcn_mfma_f32_16x16x32_bf16(ah1, bm1, a, 0, 0, 0);
      a = __builtin_amdgcn_mfma_f32_16x16x32_bf16(am0, bh0, a, 0, 0, 0);  // mh
      a = __builtin_amdgcn_mfma_f32_16x16x32_bf16(am1, bh1, a, 0, 0, 0);
      a = __builtin_amdgcn_mfma_f32_16x16x32_bf16(ah0, bh0, a, 0, 0, 0);  // hh
      a = __builtin_amdgcn_mfma_f32_16x16x32_bf16(ah1, bh1, a, 0, 0, 0);
      acc[g] = a;
    }

    // keys = sq[m] - 2*dot; lane's 32 candidates = 8 col-groups x 4 rows
    unsigned pend = 0;
    {
      float tl[4];
#pragma unroll
      for (int r = 0; r < 4; r++) tl[r] = thrS[w * 16 + q * 4 + r];
#pragma unroll
      for (int g = 0; g < 8; g++) {
        float sv = sqs[g * 16 + lm];
#pragma unroll
        for (int r = 0; r < 4; r++) {
          float key = fmaf(-2.f, acc[g][r], sv);
          acc[g][r] = key;
          if (key < tl[r]) pend |= 1u << (g * 4 + r);
        }
      }
    }

    // wave-private push / drain: NO __syncthreads (DS in-order per wave)
    for (;;) {
      if (pend) {
#pragma unroll
        for (int g = 0; g < 8; g++) {
#pragma unroll
          for (int r = 0; r < 4; r++) {
            unsigned bit = 1u << (g * 4 + r);
            if (pend & bit) {
              int row = w * 16 + q * 4 + r;
              int p = atomicAdd(&qcnt[row], 1);
              if (p < QCAP) {
                qk[row][p] = acc[g][r];
                qm[row][p] = (unsigned short)(m0 + g * 16 + lm);
                pend &= ~bit;
              }
              // else: bit stays set -> retry after drain
            }
          }
        }
      }
      unsigned long long anyovf = __ballot(pend != 0);

      if (handler) {                             // 16 lanes drain 16 rows
        int cn = qcnt[myrow];
        if (cn > QCAP) cn = QCAP;
        for (int p0 = 0; p0 < cn; p0 += 4) {
          float4 kv4 = *(const float4*)&qk[myrow][p0];
          ushort4 mv4 = *(const ushort4*)&qm[myrow][p0];
          float kva[4] = {kv4.x, kv4.y, kv4.z, kv4.w};
          unsigned short mva[4] = {mv4.x, mv4.y, mv4.z, mv4.w};
#pragma unroll
          for (int j = 0; j < 4; j++) {
            if (p0 + j < cn && kva[j] < hthr) {
              float kv = kva[j];
              int mvi = (int)mva[j];
              float mx = -INFINITY, mx2 = -INFINITY;
              int sl = 0;
#pragma unroll
              for (int kk = 0; kk < Kk; kk++) {
                float v = hk[kk];
                if (v > mx) { mx2 = mx; mx = v; sl = kk; }
                else if (v > mx2) mx2 = v;
              }
#pragma unroll
              for (int kk = 0; kk < Kk; kk++) {
                bool hit = (kk == sl);
                hk[kk] = hit ? kv : hk[kk];
                hix[kk] = hit ? mvi : hix[kk];
              }
              hthr = fmaxf(mx2, kv);
            }
          }
        }
        if (cn) { qcnt[myrow] = 0; thrS[myrow] = hthr; }
      }
      if (!anyovf) break;
      // refilter surviving bits against the tightened thresholds
      {
        float tl[4];
#pragma unroll
        for (int r = 0; r < 4; r++) tl[r] = thrS[w * 16 + q * 4 + r];
#pragma unroll
        for (int g = 0; g < 8; g++)
#pragma unroll
          for (int r = 0; r < 4; r++) {
            unsigned bit = 1u << (g * 4 + r);
            if ((pend & bit) && acc[g][r] >= tl[r]) pend &= ~bit;
          }
      }
    }
  }

  // final write: handler lane owns row myrow's list
  if (handler) {
    size_t base = ((size_t)b * Nn + n0 + myrow) * Kk;
#pragma unroll
    for (int kk = 0; kk < Kk; kk++) idxout[base + kk] = hix[kk];
  }
}

// ---------------------------------------------------------------- k_stats
__global__ __launch_bounds__(256) void k_stats(const float* __restrict__ y1,
                                               const float* __restrict__ z,
                                               const int* __restrict__ idxp,
                                               float* __restrict__ stats) {
  __shared__ float rs[4][64];
  __shared__ float rq[4][64];
  int tid = threadIdx.x;
  int o = tid & 63, g = tid >> 6;
  int b = blockIdx.x & 7;                       // XCD swizzle
  int n0 = (blockIdx.x >> 3) << 6;
  const float* y1b = y1 + (size_t)b * Nn * 64;
  float s = 0.f, ss = 0.f;
  for (int t = 0; t < 16; t++) {
    int n = n0 + g + t * 4;
    size_t base = (size_t)b * Nn + n;
    float zv = z[base * 64 + o];
    const int* ip = idxp + base * Kk;
#pragma unroll
    for (int k = 0; k < Kk; k++) {
      int j = ip[k];
      float hv = y1b[(size_t)j * 64 + o] + zv;
      s += hv;
      ss = fmaf(hv, hv, ss);
    }
  }
  rs[g][o] = s;
  rq[g][o] = ss;
  __syncthreads();
  if (tid < 64) {
    float a = rs[0][tid] + rs[1][tid] + rs[2][tid] + rs[3][tid];
    float qq = rq[0][tid] + rq[1][tid] + rq[2][tid] + rq[3][tid];
    atomicAdd(&stats[tid], a);
    atomicAdd(&stats[64 + tid], qq);
  }
}

// ---------------------------------------------------------------- k_out
__global__ __launch_bounds__(256) void k_out(const float* __restrict__ y1,
                                             const float* __restrict__ z,
                                             const int* __restrict__ idxp,
                                             const float* __restrict__ stats,
                                             const float* __restrict__ gamma,
                                             const float* __restrict__ beta,
                                             float* __restrict__ out) {
  __shared__ float T[64][65];
  int tid = threadIdx.x;
  int lane = tid & 63;
  int w = tid >> 6;
  int b = blockIdx.x & 7;                       // XCD swizzle
  int n0 = (blockIdx.x >> 3) << 6;
  int o = lane;
  const float inv = 1.0f / (float)NTOT;
  float mean = stats[o] * inv;
  float var = fmaf(-mean, mean, stats[64 + o] * inv);
  float sc = gamma[o] * rsqrtf(var + 1e-5f);
  float bi = fmaf(-mean, sc, beta[o]);
  const float* y1b = y1 + (size_t)b * Nn * 64;
  for (int t = 0; t < 16; t++) {
    int nl = w + t * 4;
    size_t base = (size_t)b * Nn + n0 + nl;
    float zv = z[base * 64 + o];
    const int* ip = idxp + base * Kk;
    float mv = -INFINITY;
#pragma unroll
    for (int k = 0; k < Kk; k++) {
      int j = ip[k];
      float hv = y1b[(size_t)j * 64 + o] + zv;
      float hn = fmaf(hv, sc, bi);
      float a = (hn >= 0.f) ? hn : 0.2f * hn;
      mv = fmaxf(mv, a);
    }
    T[o][nl] = mv;
  }
  __syncthreads();
  for (int t = 0; t < 16; t++) {
    int oo = w * 16 + t;
    out[((size_t)b * Oo + oo) * Nn + n0 + lane] = T[oo][lane];
  }
}

// ---------------------------------------------------------------- launch
extern "C" void kernel_launch(void* const* d_in, const int* in_sizes, int n_in,
                              void* d_out, int out_size, void* d_ws, size_t ws_size,
                              hipStream_t stream) {
  const float* x = (const float*)d_in[0];
  const float* W = (const float*)d_in[1];
  const float* gamma = (const float*)d_in[2];
  const float* beta = (const float*)d_in[3];
  // d_in[4] is k (=20), baked in as Kk.

  // workspace layout (bytes):
  //   xhi  : [0,        4194304)  bf16 [b][n][c]  \  dead after k_knn;
  //   xmid : [4194304,  8388608)  bf16 [b][n][c]   } y1 overlays [0,8M),
  //   xlo  : [8388608, 12582912)  bf16 [b][n][c]  /  z overlays [8M,16M)
  //   y1   : [0,        8388608)  B*N*O fp32  (written by k_y1z, after k_knn)
  //   z    : [8388608, 16777216)  B*N*O fp32  (written by k_y1z, after k_knn)
  //   sq   : [16777216,16908288)  B*N fp32
  //   stats: [16908288,16908800)  128 fp32
  //   idx  : [16908800,19530240)  B*N*K int32
  char* ws = (char*)d_ws;
  unsigned short* xhi = (unsigned short*)ws;
  unsigned short* xmid = (unsigned short*)(ws + 4194304);
  unsigned short* xlo = (unsigned short*)(ws + 8388608);
  float* y1 = (float*)ws;
  float* z = (float*)(ws + 8388608);
  float* sq = (float*)(ws + 16777216);
  float* stats = (float*)(ws + 16908288);
  int* idx = (int*)(ws + 16908800);
  float* out = (float*)d_out;

  hipMemsetAsync(stats, 0, 128 * sizeof(float), stream);
  k_split<<<Bn * (Nn / 64), 256, 0, stream>>>(x, xhi, xmid, xlo);
  k_sq<<<(Bn * Nn) / 256, 256, 0, stream>>>(x, sq);
  k_knn<<<Bn * (Nn / 64), 256, 0, stream>>>(xhi, xmid, xlo, sq, idx);
  k_y1z<<<Bn * (Nn / 64), 256, 0, stream>>>(x, W, y1, z);
  k_stats<<<Bn * (Nn / 64), 256, 0, stream>>>(y1, z, idx, stats);
  k_out<<<Bn * (Nn / 64), 256, 0, stream>>>(y1, z, idx, stats, gamma, beta, out);
}